// Round 19
// baseline (194.288 us; speedup 1.0000x reference)
//
#include <hip/hip_runtime.h>

// AdaIN on MI355X — 4-dispatch pipeline, MFMA segment reduction.
// content: (Nc=1e6, C=64) f32, style: (2.5e5, 64) f32, B=16 segments.
// Reduce = segment-sum-as-MFMA (S=E^T·X, Q=E^T·X², one-hot A from idx).
// R16 (champion 182us): dbuf + __syncthreads -> vmcnt(0) drain each tile =
// one tile in flight (the m97 barrier-drain stall). R19: T3/T4 pipeline —
// 3 tile buffers, UNIFORM 3 VMEM ops/wave/phase, s_waitcnt vmcnt(7) (never
// 0) + raw s_barrier pair, loop unrolled x3 (static buffers/regs).
// memset -> mfma reduce -> finalize -> apply.

#define NB 16          // num_batches
#define NC 64          // channels
#define NREP 16        // global partial-buffer replicas
#define CBLKS 1024     // content blocks } 1280 total = 5 blocks/CU (32KB LDS)
#define SBLKS 256      // style blocks   } ~30.5 tiles per block each

typedef float fvec4 __attribute__((ext_vector_type(4)));   // nontemporal-ok
typedef float f32x4 __attribute__((ext_vector_type(4)));
typedef short bf16x8 __attribute__((ext_vector_type(8)));

// ws float-offset layout:
#define WS_CPART 0                        // NREP * 2048 (sum[1024], sumsq[1024])
#define WS_SPART (NREP * 2048)            // NREP * 2048
#define WS_CCNT  (2 * NREP * 2048)        // NREP * 16
#define WS_SCNT  (WS_CCNT + NREP * NB)    // NREP * 16
#define WS_SCALE (WS_SCNT + NREP * NB)    // 1024
#define WS_BIAS  (WS_SCALE + 1024)        // 1024
#define WS_ZERO_FLOATS WS_SCALE

__device__ __forceinline__ unsigned cvtpk(float lo, float hi)
{
    unsigned r;
    asm("v_cvt_pk_bf16_f32 %0, %1, %2" : "=v"(r) : "v"(lo), "v"(hi));
    return r;
}

__device__ __forceinline__ void gload16(const float* g, float* l)
{
    // async global->LDS, 16B/lane; LDS dest = base + lane*16 (linear).
    __builtin_amdgcn_global_load_lds(
        (const __attribute__((address_space(1))) void*)g,
        (__attribute__((address_space(3))) void*)l, 16, 0, 0);
}

// Stage one 32-row tile into bufp (2048 floats). Wave wv issues EXACTLY 2
// gload16 (uniform, clamped addressing — no conditional issue).
// LDS (row, c4') holds global c4 = c4' ^ 2*((row>>3)&3) (src-side swizzle,
// verified R16); read side applies the same involution -> 2-way banks.
__device__ __forceinline__ void stage_tile(
    const float* __restrict__ feats, int nrows, int rb, int wv, int lane,
    float* bufp)
{
    #pragma unroll
    for (int u = 0; u < 2; ++u) {
        const int i = 2 * wv + u;
        int rg = rb + i * 4 + (lane >> 4);
        if (rg > nrows - 1) rg = nrows - 1;            // pad rows unused (A=0)
        const int c4 = (lane & 15) ^ (2 * ((i >> 1) & 3));
        gload16(feats + (size_t)rg * NC + c4 * 4, bufp + i * 256);
    }
}

// Uniform-issue idx load for tile ct: exactly ONE VMEM instruction.
__device__ __forceinline__ int idx_load(
    const int* __restrict__ idx, int nrows, int ct, int lane)
{
    const int rl = (ct << 5) + (lane & 31);
    int rc = rl; if (rc > nrows - 1) rc = nrows - 1;   // clamp addr, uncond load
    const int raw = idx[rc];
    return (rl < nrows) ? raw : -1;
}

__device__ __forceinline__ void reduce_body(
    const float* __restrict__ feats, const int* __restrict__ idx, int nrows,
    float* __restrict__ part, float* __restrict__ cntp,
    int blk, int nblk, int tid, float* buf /*3*2048*/, float* lsum /*2048*/)
{
    const int lane = tid & 63;
    const int wv   = tid >> 6;             // wave = channel-quarter
    const int half = lane >> 4;            // k-group 0..3
    const int sub  = lane & 15;            // A-row (batch) / B-col (channel)

    f32x4 accS = {0, 0, 0, 0}, accQ = {0, 0, 0, 0};
    int cnti = 0;

    const int ntiles = (nrows + 31) >> 5;  // 32-row tiles
    const int tpb = (ntiles + nblk - 1) / nblk;
    const int t0 = blk * tpb;
    const int t1 = (t0 + tpb < ntiles) ? (t0 + tpb) : ntiles;

    // swizzled ds_read base (float index); element j adds j*NC
    const int c4p   = (wv * 4 + (sub >> 2)) ^ (2 * half);
    const int rbase = half * 8 * NC + c4p * 4 + (sub & 3);

#define CLAMPT(x) (((x) < t1) ? (x) : (t1 - 1))

    // Consume tile t from buffer bi using batch vector vv.
    // vmcnt(7): 7 newer VMEM ops (1 idx + 2x[stage2+idx]) -> this tile's
    // 2 stage ops retired. Raw barriers: NO vmcnt(0) drain (T4).
#define CONSUME(bi, vv) do {                                                 \
        asm volatile("s_waitcnt vmcnt(7)" ::: "memory");                     \
        __builtin_amdgcn_sched_barrier(0);                                   \
        __builtin_amdgcn_s_barrier();                                        \
        __builtin_amdgcn_sched_barrier(0);                                   \
        _Pragma("unroll")                                                    \
        for (int bb = 0; bb < 4; ++bb) {                                     \
            const int b = wv * 4 + bb;                                       \
            const unsigned long long m = __ballot((vv) == b) & 0xFFFFFFFFull;\
            cnti += (lane == b) ? (int)__popcll(m) : 0;                      \
        }                                                                    \
        union { unsigned w[4]; bf16x8 v; } A;                                \
        const int kb4 = half * 32;                                           \
        _Pragma("unroll")                                                    \
        for (int i = 0; i < 4; ++i) {                                        \
            const int k0 = __builtin_amdgcn_ds_bpermute(kb4 + 8 * i,     (vv));\
            const int k1 = __builtin_amdgcn_ds_bpermute(kb4 + 8 * i + 4, (vv));\
            const unsigned lo = (k0 == sub) ? 0x3F80u     : 0u;              \
            const unsigned hi = (k1 == sub) ? 0x3F800000u : 0u;              \
            A.w[i] = lo | hi;                                                \
        }                                                                    \
        const float* bp = buf + (bi) * 2048;                                 \
        float xv[8];                                                         \
        _Pragma("unroll")                                                    \
        for (int j = 0; j < 8; ++j) xv[j] = bp[rbase + j * NC];              \
        union { unsigned w[4]; bf16x8 v; } Bs, Bq;                           \
        _Pragma("unroll")                                                    \
        for (int i = 0; i < 4; ++i) {                                        \
            const float a0 = xv[2 * i], a1 = xv[2 * i + 1];                  \
            Bs.w[i] = cvtpk(a0, a1);                                         \
            Bq.w[i] = cvtpk(a0 * a0, a1 * a1);                               \
        }                                                                    \
        accS = __builtin_amdgcn_mfma_f32_16x16x32_bf16(A.v, Bs.v, accS, 0, 0, 0);\
        accQ = __builtin_amdgcn_mfma_f32_16x16x32_bf16(A.v, Bq.v, accQ, 0, 0, 0);\
        __builtin_amdgcn_sched_barrier(0);                                   \
        __builtin_amdgcn_s_barrier();      /* all waves done reading bi */   \
        __builtin_amdgcn_sched_barrier(0);                                   \
    } while (0)

    // Refill buffer bi with tile t+3 (clamped: uniform 3 VMEM ops always).
#define STAGE3(bi, vv, tcur) do {                                            \
        const int ct = CLAMPT((tcur) + 3);                                   \
        stage_tile(feats, nrows, ct << 5, wv, lane, buf + (bi) * 2048);      \
        (vv) = idx_load(idx, nrows, ct, lane);                               \
    } while (0)

    if (t0 < t1) {
        int v0, v1, v2;
        // prologue: fill 3 buffers (clamped duplicates if <3 tiles)
        stage_tile(feats, nrows, t0 << 5, wv, lane, buf);
        v0 = idx_load(idx, nrows, t0, lane);
        stage_tile(feats, nrows, CLAMPT(t0 + 1) << 5, wv, lane, buf + 2048);
        v1 = idx_load(idx, nrows, CLAMPT(t0 + 1), lane);
        stage_tile(feats, nrows, CLAMPT(t0 + 2) << 5, wv, lane, buf + 4096);
        v2 = idx_load(idx, nrows, CLAMPT(t0 + 2), lane);

        int t = t0;
        for (;;) {
            CONSUME(0, v0); STAGE3(0, v0, t); if (++t >= t1) break;
            CONSUME(1, v1); STAGE3(1, v1, t); if (++t >= t1) break;
            CONSUME(2, v2); STAGE3(2, v2, t); if (++t >= t1) break;
        }
    }
#undef CONSUME
#undef STAGE3
#undef CLAMPT

    // ---- merge: wave owns channels [wv*16, wv*16+16) exclusively ----
    // D layout (HW-verified R11): col = sub, row(batch) = half*4 + reg.
    #pragma unroll
    for (int i = 0; i < 4; ++i) {
        const int m = half * 4 + i;
        lsum[m * NC + wv * 16 + sub]        = accS[i];
        lsum[1024 + m * NC + wv * 16 + sub] = accQ[i];
    }
    __syncthreads();                       // full drain (also pending stages)
    float* dst = part + (blk & (NREP - 1)) * 2048;
    for (int i = tid; i < 2048; i += 256)
        atomicAdd(&dst[i], lsum[i]);
    // wave wv counted batches 4wv..4wv+3 (held in lanes 4wv..4wv+3)
    if ((lane >> 2) == wv && lane < NB)
        atomicAdd(&cntp[(blk & (NREP - 1)) * NB + lane], (float)cnti);
}

__global__ __launch_bounds__(256) void reduce_stats(
    const float* __restrict__ content, const int* __restrict__ ci, int Nc,
    const float* __restrict__ style,   const int* __restrict__ si, int Ns,
    float* __restrict__ ws)
{
    __shared__ float buf[3 * 2048];        // 24 KB triple-buffered tiles
    __shared__ float lsum[2048];           // 8 KB merge buffer
    if (blockIdx.x < CBLKS)
        reduce_body(content, ci, Nc, ws + WS_CPART, ws + WS_CCNT,
                    blockIdx.x, CBLKS, threadIdx.x, buf, lsum);
    else
        reduce_body(style, si, Ns, ws + WS_SPART, ws + WS_SCNT,
                    blockIdx.x - CBLKS, SBLKS, threadIdx.x, buf, lsum);
}

__global__ void finalize_kernel(float* __restrict__ ws)
{
    if (threadIdx.x >= NC) return;
    const int c = threadIdx.x;
    const float* c_part = ws + WS_CPART;
    const float* s_part = ws + WS_SPART;
    const float* c_cntp = ws + WS_CCNT;
    const float* s_cntp = ws + WS_SCNT;
    float* scale = ws + WS_SCALE;
    float* bias  = ws + WS_BIAS;

    float gm = 0.f, gs = 0.f;
    for (int b = 0; b < NB; ++b) {
        float csum = 0.f, csq = 0.f, ssum = 0.f, ssq = 0.f, ccnt = 0.f, scnt = 0.f;
        #pragma unroll
        for (int rep = 0; rep < NREP; ++rep) {
            csum += c_part[rep * 2048 + b * NC + c];
            csq  += c_part[rep * 2048 + 1024 + b * NC + c];
            ssum += s_part[rep * 2048 + b * NC + c];
            ssq  += s_part[rep * 2048 + 1024 + b * NC + c];
            ccnt += c_cntp[rep * NB + b];
            scnt += s_cntp[rep * NB + b];
        }
        const float smean = ssum / scnt;
        const float svar  = (ssq - scnt * smean * smean) / (scnt - 1.0f);
        const float sstd  = sqrtf(fmaxf(svar, 0.f)) + 1e-8f;
        if (b == 0) { gm = smean; gs = sstd; }
        else        { gm = 0.9f * gm + 0.1f * smean; gs = 0.9f * gs + 0.1f * sstd; }
        const float cmean = csum / ccnt;
        const float cvar  = (csq - ccnt * cmean * cmean) / (ccnt - 1.0f);
        const float cstd  = sqrtf(fmaxf(cvar, 0.f)) + 1e-8f;
        const float sc = gs / cstd;        // out = sc*x + bi
        scale[b * NC + c] = sc;
        bias [b * NC + c] = gm - sc * cmean;
    }
}

__global__ __launch_bounds__(256) void apply_kernel(
    const float* __restrict__ content, const int* __restrict__ ci, int Nc,
    const float* __restrict__ ws, fvec4* __restrict__ out4)
{
    __shared__ fvec4 s_sc[NB * 17];        // stride-17 pad
    __shared__ fvec4 s_bi[NB * 17];
    const fvec4* scale4 = (const fvec4*)(ws + WS_SCALE);
    const fvec4* bias4  = (const fvec4*)(ws + WS_BIAS);
    for (int i = threadIdx.x; i < NB * 16; i += 256) {
        const int b = i >> 4, c4 = i & 15;
        s_sc[b * 17 + c4] = scale4[i];
        s_bi[b * 17 + c4] = bias4[i];
    }
    __syncthreads();

    const fvec4* feats4 = (const fvec4*)content;
    const int total4 = Nc * 16;
    const int stride = gridDim.x * 256;
    for (int i = blockIdx.x * 256 + threadIdx.x; i < total4; i += stride) {
        const int r  = i >> 4;
        const int c4 = i & 15;
        const int b  = ci[r];
        const fvec4 v  = feats4[i];
        const fvec4 sc = s_sc[b * 17 + c4];
        const fvec4 bi = s_bi[b * 17 + c4];
        fvec4 o;
        o.x = fmaf(sc.x, v.x, bi.x);
        o.y = fmaf(sc.y, v.y, bi.y);
        o.z = fmaf(sc.z, v.z, bi.z);
        o.w = fmaf(sc.w, v.w, bi.w);
        __builtin_nontemporal_store(o, &out4[i]);
    }
}

extern "C" void kernel_launch(void* const* d_in, const int* in_sizes, int n_in,
                              void* d_out, int out_size, void* d_ws, size_t ws_size,
                              hipStream_t stream)
{
    const float* content = (const float*)d_in[0];
    const float* style   = (const float*)d_in[1];
    const int*   ci      = (const int*)d_in[2];
    const int*   si      = (const int*)d_in[3];

    const int Nc = in_sizes[0] / NC;   // 1,000,000
    const int Ns = in_sizes[1] / NC;   //   250,000

    float* ws = (float*)d_ws;
    // ws never re-poisoned between replays: zero accumulators every call.
    (void)hipMemsetAsync(ws, 0, WS_ZERO_FLOATS * sizeof(float), stream);

    reduce_stats<<<CBLKS + SBLKS, 256, 0, stream>>>(content, ci, Nc, style, si, Ns, ws);
    finalize_kernel<<<1, 64, 0, stream>>>(ws);
    apply_kernel<<<2048, 256, 0, stream>>>(content, ci, Nc, ws, (fvec4*)d_out);
}

// Round 20
// 182.386 us; speedup vs baseline: 1.0653x; 1.0653x over previous
//
#include <hip/hip_runtime.h>

// AdaIN on MI355X — 4-dispatch pipeline, MFMA segment reduction.
// content: (Nc=1e6, C=64) f32, style: (2.5e5, 64) f32, B=16 segments.
// Reduce = segment-sum-as-MFMA (S=E^T·X, Q=E^T·X², one-hot A from idx).
// CHAMPION (R16, 182.2us): global_load_lds staging with SOURCE-side XOR
// swizzle (dest linear), double-buffered tiles -> one barrier per tile,
// 24KB LDS -> 6 blocks/CU. Reverted here after R17 (128-row tile: broken),
// R18 (distributed ballots: neutral), R19 (counted-vmcnt pipeline: -12us,
// occupancy 31%, sched_barrier defeated compiler overlap).
// memset -> mfma reduce -> finalize -> apply.

#define NB 16          // num_batches
#define NC 64          // channels
#define NREP 16        // global partial-buffer replicas
#define CBLKS 1228     // content blocks } 1536 total = 6 blocks/CU
#define SBLKS 308      // style blocks   } (~26 tiles per block both)

typedef float fvec4 __attribute__((ext_vector_type(4)));   // nontemporal-ok
typedef float f32x4 __attribute__((ext_vector_type(4)));
typedef short bf16x8 __attribute__((ext_vector_type(8)));

// ws float-offset layout:
#define WS_CPART 0                        // NREP * 2048 (sum[1024], sumsq[1024])
#define WS_SPART (NREP * 2048)            // NREP * 2048
#define WS_CCNT  (2 * NREP * 2048)        // NREP * 16
#define WS_SCNT  (WS_CCNT + NREP * NB)    // NREP * 16
#define WS_SCALE (WS_SCNT + NREP * NB)    // 1024
#define WS_BIAS  (WS_SCALE + 1024)        // 1024
#define WS_ZERO_FLOATS WS_SCALE

__device__ __forceinline__ unsigned cvtpk(float lo, float hi)
{
    unsigned r;
    asm("v_cvt_pk_bf16_f32 %0, %1, %2" : "=v"(r) : "v"(lo), "v"(hi));
    return r;
}

__device__ __forceinline__ void gload16(const float* g, float* l)
{
    // async global->LDS, 16B/lane; LDS dest = base + lane*16 (linear).
    __builtin_amdgcn_global_load_lds(
        (const __attribute__((address_space(1))) void*)g,
        (__attribute__((address_space(3))) void*)l, 16, 0, 0);
}

// Stage tile t into bufp (2048 floats). Wave wv issues instrs {2wv, 2wv+1}.
// LDS float (row, c4') holds global (rb+row, ch4 = c4' ^ 2*(row>>3)):
// source-side swizzle, linear dest. Read side: conflict-free 2-way.
__device__ __forceinline__ void stage_tile(
    const float* __restrict__ feats, int nrows, int rb, int wv, int lane,
    float* bufp)
{
    #pragma unroll
    for (int u = 0; u < 2; ++u) {
        const int i = 2 * wv + u;
        int rg = rb + i * 4 + (lane >> 4);
        if (rg > nrows - 1) rg = nrows - 1;            // pad rows unused (A=0)
        const int c4 = (lane & 15) ^ (2 * ((i >> 1) & 3));
        gload16(feats + (size_t)rg * NC + c4 * 4, bufp + i * 256);
    }
}

__device__ __forceinline__ void reduce_body(
    const float* __restrict__ feats, const int* __restrict__ idx, int nrows,
    float* __restrict__ part, float* __restrict__ cntp,
    int blk, int nblk, int tid, float* buf /*2*2048*/, float* lsum /*2048*/)
{
    const int lane = tid & 63;
    const int wv   = tid >> 6;             // wave = channel-quarter
    const int half = lane >> 4;            // k-group 0..3
    const int sub  = lane & 15;            // A-row (batch) / B-col (channel)

    f32x4 accS = {0, 0, 0, 0}, accQ = {0, 0, 0, 0};
    int cnti = 0;

    const int ntiles = (nrows + 31) >> 5;  // 32-row tiles
    const int tpb = (ntiles + nblk - 1) / nblk;
    const int t0 = blk * tpb;
    const int t1 = (t0 + tpb < ntiles) ? (t0 + tpb) : ntiles;

    // swizzled ds_read base for this lane (float index), +j*64 per element
    const int c4p   = (wv * 4 + (sub >> 2)) ^ (2 * half);
    const int rbase = half * 8 * NC + c4p * 4 + (sub & 3);

    int vidx = -1;
    if (t0 < t1) {
        stage_tile(feats, nrows, t0 << 5, wv, lane, buf);
        const int rl = (t0 << 5) + (lane & 31);
        vidx = (rl < nrows) ? idx[rl] : -1;
    }

    int cur = 0;
    for (int t = t0; t < t1; ++t) {
        __syncthreads();                   // drains vmcnt -> buf[cur] staged

        // issue next tile's staging immediately (flies across reads+MFMA)
        if (t + 1 < t1)
            stage_tile(feats, nrows, (t + 1) << 5, wv, lane, buf + (cur ^ 1) * 2048);
        int vn = -1;
        if (t + 1 < t1) {
            const int rl = ((t + 1) << 5) + (lane & 31);
            vn = (rl < nrows) ? idx[rl] : -1;
        }

        // ---- counts (wave 0; lanes 0-31 carry the tile's rows) ----
        if (wv == 0) {
            #pragma unroll
            for (int b = 0; b < NB; ++b) {
                const unsigned long long m = __ballot(vidx == b) & 0xFFFFFFFFull;
                cnti += (lane == b) ? (int)__popcll(m) : 0;
            }
        }

        // ---- A fragment: one-hot E^T, elem pair (2i,2i+1), k = half*8+.. ----
        union { unsigned w[4]; bf16x8 v; } A;
        const int kb4 = half * 32;
        #pragma unroll
        for (int i = 0; i < 4; ++i) {
            const int k0 = __builtin_amdgcn_ds_bpermute(kb4 + 8 * i,     vidx);
            const int k1 = __builtin_amdgcn_ds_bpermute(kb4 + 8 * i + 4, vidx);
            const unsigned lo = (k0 == sub) ? 0x3F80u     : 0u;   // bf16(1.0)
            const unsigned hi = (k1 == sub) ? 0x3F800000u : 0u;
            A.w[i] = lo | hi;
        }

        // ---- B from LDS (swizzled, conflict-free): elem j = X[..][wv*16+sub] ----
        const float* bp = buf + cur * 2048;
        float xv[8];
        #pragma unroll
        for (int j = 0; j < 8; ++j)
            xv[j] = bp[rbase + j * NC];

        union { unsigned w[4]; bf16x8 v; } Bs, Bq;
        #pragma unroll
        for (int i = 0; i < 4; ++i) {
            const float a0 = xv[2 * i], a1 = xv[2 * i + 1];
            Bs.w[i] = cvtpk(a0, a1);
            Bq.w[i] = cvtpk(a0 * a0, a1 * a1);
        }

        accS = __builtin_amdgcn_mfma_f32_16x16x32_bf16(A.v, Bs.v, accS, 0, 0, 0);
        accQ = __builtin_amdgcn_mfma_f32_16x16x32_bf16(A.v, Bq.v, accQ, 0, 0, 0);

        vidx = vn;
        cur ^= 1;
    }

    // ---- merge: wave owns channels [wv*16, wv*16+16) exclusively ----
    // D layout (HW-verified R11): col = sub, row(batch) = half*4 + reg.
    #pragma unroll
    for (int i = 0; i < 4; ++i) {
        const int m = half * 4 + i;
        lsum[m * NC + wv * 16 + sub]        = accS[i];
        lsum[1024 + m * NC + wv * 16 + sub] = accQ[i];
    }
    __syncthreads();
    float* dst = part + (blk & (NREP - 1)) * 2048;
    for (int i = tid; i < 2048; i += 256)
        atomicAdd(&dst[i], lsum[i]);
    if (wv == 0 && lane < NB)
        atomicAdd(&cntp[(blk & (NREP - 1)) * NB + lane], (float)cnti);
}

__global__ __launch_bounds__(256) void reduce_stats(
    const float* __restrict__ content, const int* __restrict__ ci, int Nc,
    const float* __restrict__ style,   const int* __restrict__ si, int Ns,
    float* __restrict__ ws)
{
    __shared__ float buf[2 * 2048];        // 16 KB double-buffered tiles
    __shared__ float lsum[2048];           // 8 KB merge buffer
    if (blockIdx.x < CBLKS)
        reduce_body(content, ci, Nc, ws + WS_CPART, ws + WS_CCNT,
                    blockIdx.x, CBLKS, threadIdx.x, buf, lsum);
    else
        reduce_body(style, si, Ns, ws + WS_SPART, ws + WS_SCNT,
                    blockIdx.x - CBLKS, SBLKS, threadIdx.x, buf, lsum);
}

__global__ void finalize_kernel(float* __restrict__ ws)
{
    if (threadIdx.x >= NC) return;
    const int c = threadIdx.x;
    const float* c_part = ws + WS_CPART;
    const float* s_part = ws + WS_SPART;
    const float* c_cntp = ws + WS_CCNT;
    const float* s_cntp = ws + WS_SCNT;
    float* scale = ws + WS_SCALE;
    float* bias  = ws + WS_BIAS;

    float gm = 0.f, gs = 0.f;
    for (int b = 0; b < NB; ++b) {
        float csum = 0.f, csq = 0.f, ssum = 0.f, ssq = 0.f, ccnt = 0.f, scnt = 0.f;
        #pragma unroll
        for (int rep = 0; rep < NREP; ++rep) {
            csum += c_part[rep * 2048 + b * NC + c];
            csq  += c_part[rep * 2048 + 1024 + b * NC + c];
            ssum += s_part[rep * 2048 + b * NC + c];
            ssq  += s_part[rep * 2048 + 1024 + b * NC + c];
            ccnt += c_cntp[rep * NB + b];
            scnt += s_cntp[rep * NB + b];
        }
        const float smean = ssum / scnt;
        const float svar  = (ssq - scnt * smean * smean) / (scnt - 1.0f);
        const float sstd  = sqrtf(fmaxf(svar, 0.f)) + 1e-8f;
        if (b == 0) { gm = smean; gs = sstd; }
        else        { gm = 0.9f * gm + 0.1f * smean; gs = 0.9f * gs + 0.1f * sstd; }
        const float cmean = csum / ccnt;
        const float cvar  = (csq - ccnt * cmean * cmean) / (ccnt - 1.0f);
        const float cstd  = sqrtf(fmaxf(cvar, 0.f)) + 1e-8f;
        const float sc = gs / cstd;        // out = sc*x + bi
        scale[b * NC + c] = sc;
        bias [b * NC + c] = gm - sc * cmean;
    }
}

__global__ __launch_bounds__(256) void apply_kernel(
    const float* __restrict__ content, const int* __restrict__ ci, int Nc,
    const float* __restrict__ ws, fvec4* __restrict__ out4)
{
    __shared__ fvec4 s_sc[NB * 17];        // stride-17 pad
    __shared__ fvec4 s_bi[NB * 17];
    const fvec4* scale4 = (const fvec4*)(ws + WS_SCALE);
    const fvec4* bias4  = (const fvec4*)(ws + WS_BIAS);
    for (int i = threadIdx.x; i < NB * 16; i += 256) {
        const int b = i >> 4, c4 = i & 15;
        s_sc[b * 17 + c4] = scale4[i];
        s_bi[b * 17 + c4] = bias4[i];
    }
    __syncthreads();

    const fvec4* feats4 = (const fvec4*)content;
    const int total4 = Nc * 16;
    const int stride = gridDim.x * 256;
    for (int i = blockIdx.x * 256 + threadIdx.x; i < total4; i += stride) {
        const int r  = i >> 4;
        const int c4 = i & 15;
        const int b  = ci[r];
        const fvec4 v  = feats4[i];
        const fvec4 sc = s_sc[b * 17 + c4];
        const fvec4 bi = s_bi[b * 17 + c4];
        fvec4 o;
        o.x = fmaf(sc.x, v.x, bi.x);
        o.y = fmaf(sc.y, v.y, bi.y);
        o.z = fmaf(sc.z, v.z, bi.z);
        o.w = fmaf(sc.w, v.w, bi.w);
        __builtin_nontemporal_store(o, &out4[i]);
    }
}

extern "C" void kernel_launch(void* const* d_in, const int* in_sizes, int n_in,
                              void* d_out, int out_size, void* d_ws, size_t ws_size,
                              hipStream_t stream)
{
    const float* content = (const float*)d_in[0];
    const float* style   = (const float*)d_in[1];
    const int*   ci      = (const int*)d_in[2];
    const int*   si      = (const int*)d_in[3];

    const int Nc = in_sizes[0] / NC;   // 1,000,000
    const int Ns = in_sizes[1] / NC;   //   250,000

    float* ws = (float*)d_ws;
    // ws never re-poisoned between replays: zero accumulators every call.
    (void)hipMemsetAsync(ws, 0, WS_ZERO_FLOATS * sizeof(float), stream);

    reduce_stats<<<CBLKS + SBLKS, 256, 0, stream>>>(content, ci, Nc, style, si, Ns, ws);
    finalize_kernel<<<1, 64, 0, stream>>>(ws);
    apply_kernel<<<2048, 256, 0, stream>>>(content, ci, Nc, ws, (fvec4*)d_out);
}